// Round 1
// baseline (2875.366 us; speedup 1.0000x reference)
//
#include <hip/hip_runtime.h>
#include <math.h>

#define T_SEQ 4096
#define DM 1024
#define NH 16
#define HD 64

// C[M][N] = A[M][K] @ B[N][K]^T + bias[N]   (all fp32, M,N,K multiples of 64/16)
__global__ __launch_bounds__(256)
void gemm_bt_bias(const float* __restrict__ A, const float* __restrict__ B,
                  const float* __restrict__ bias, float* __restrict__ C,
                  int M, int N, int K) {
    const int BM = 64, BN = 64, BK = 16;
    __shared__ __align__(16) float As[BK][BM + 4];
    __shared__ __align__(16) float Bs[BK][BN + 4];
    const int tid = threadIdx.x;
    const int tx = tid & 15, ty = tid >> 4;
    const int m0 = blockIdx.y * BM, n0 = blockIdx.x * BN;
    float acc[4][4] = {};
    for (int k0 = 0; k0 < K; k0 += BK) {
        // stage A,B tiles (transposed into LDS): 64 rows x 16 cols each, float4 loads
        {
            int idx = tid;  // 256 float4-loads per matrix, exactly one per thread
            int r = idx >> 2, c = (idx & 3) * 4;
            float4 a = *(const float4*)&A[(size_t)(m0 + r) * K + k0 + c];
            As[c + 0][r] = a.x; As[c + 1][r] = a.y; As[c + 2][r] = a.z; As[c + 3][r] = a.w;
            float4 b = *(const float4*)&B[(size_t)(n0 + r) * K + k0 + c];
            Bs[c + 0][r] = b.x; Bs[c + 1][r] = b.y; Bs[c + 2][r] = b.z; Bs[c + 3][r] = b.w;
        }
        __syncthreads();
        #pragma unroll
        for (int k = 0; k < BK; ++k) {
            float4 a = *(const float4*)&As[k][ty * 4];
            float4 b = *(const float4*)&Bs[k][tx * 4];
            float av[4] = {a.x, a.y, a.z, a.w};
            float bv[4] = {b.x, b.y, b.z, b.w};
            #pragma unroll
            for (int i = 0; i < 4; ++i)
                #pragma unroll
                for (int j = 0; j < 4; ++j)
                    acc[i][j] += av[i] * bv[j];
        }
        __syncthreads();
    }
    #pragma unroll
    for (int i = 0; i < 4; ++i) {
        #pragma unroll
        for (int j = 0; j < 4; ++j) {
            int m = m0 + ty * 4 + i, n = n0 + tx * 4 + j;
            C[(size_t)m * N + n] = acc[i][j] + bias[n];
        }
    }
}

// Flash-style causal attention. qkv: (T, 3*DM) fp32. y: (T, DM) fp32.
// Block = (head, 64-query tile). 256 threads: thread (qi = tid>>2, kg = tid&3)
// owns query row qi, key/dim quarter kg (16 keys for scores, 16 dims for O).
__global__ __launch_bounds__(256)
void attn_causal(const float* __restrict__ qkv, float* __restrict__ y) {
    const int h  = blockIdx.y;
    const int qt = blockIdx.x;
    const int tid = threadIdx.x;
    const int qi = tid >> 2;
    const int kg = tid & 3;
    __shared__ __align__(16) float Qs[64][HD + 4];
    __shared__ __align__(16) float Ks[64][HD + 4];
    __shared__ __align__(16) float Vs[64][HD + 4];
    __shared__ __align__(16) float Ps[64][HD + 4];
    const int q0 = qt * 64;
    const size_t rs = 3 * DM;
    const int cq = h * HD;

    // stage Q tile
    for (int idx = tid; idx < 64 * 16; idx += 256) {
        int r = idx >> 4, c = (idx & 15) * 4;
        *(float4*)&Qs[r][c] = *(const float4*)&qkv[(size_t)(q0 + r) * rs + cq + c];
    }
    __syncthreads();
    // hoist my q row to registers
    float4 q4[16];
    #pragma unroll
    for (int d = 0; d < 16; ++d) q4[d] = *(const float4*)&Qs[qi][d * 4];

    float m = -INFINITY, l = 0.f;
    float acc[16];
    #pragma unroll
    for (int j = 0; j < 16; ++j) acc[j] = 0.f;

    for (int kt = 0; kt <= qt; ++kt) {
        __syncthreads();  // protect Ks/Vs/Ps from prior iteration readers
        const int k0 = kt * 64;
        for (int idx = tid; idx < 64 * 16; idx += 256) {
            int r = idx >> 4, c = (idx & 15) * 4;
            *(float4*)&Ks[r][c] = *(const float4*)&qkv[(size_t)(k0 + r) * rs + DM + cq + c];
            *(float4*)&Vs[r][c] = *(const float4*)&qkv[(size_t)(k0 + r) * rs + 2 * DM + cq + c];
        }
        __syncthreads();

        // scores for my 16 keys
        float s[16];
        #pragma unroll
        for (int j = 0; j < 16; ++j) {
            int kk = kg * 16 + j;
            float dot = 0.f;
            #pragma unroll
            for (int d = 0; d < 16; ++d) {
                float4 kv = *(const float4*)&Ks[kk][d * 4];
                dot += q4[d].x * kv.x + q4[d].y * kv.y + q4[d].z * kv.z + q4[d].w * kv.w;
            }
            s[j] = (k0 + kk <= q0 + qi) ? dot * 0.125f : -INFINITY;
        }
        // online softmax: row reduce across 4 lanes (same wave, lanes qi*4+kg)
        float tmax = s[0];
        #pragma unroll
        for (int j = 1; j < 16; ++j) tmax = fmaxf(tmax, s[j]);
        tmax = fmaxf(tmax, __shfl_xor(tmax, 1));
        tmax = fmaxf(tmax, __shfl_xor(tmax, 2));
        float mnew  = fmaxf(m, tmax);
        float alpha = __expf(m - mnew);   // m=-inf first iter -> alpha=0
        float psum = 0.f;
        #pragma unroll
        for (int j = 0; j < 16; ++j) { float p = __expf(s[j] - mnew); s[j] = p; psum += p; }
        psum += __shfl_xor(psum, 1);
        psum += __shfl_xor(psum, 2);
        l = l * alpha + psum;
        m = mnew;
        #pragma unroll
        for (int j = 0; j < 16; ++j) acc[j] *= alpha;
        // publish probabilities
        #pragma unroll
        for (int j = 0; j < 4; ++j)
            *(float4*)&Ps[qi][kg * 16 + j * 4] =
                make_float4(s[j*4], s[j*4+1], s[j*4+2], s[j*4+3]);
        __syncthreads();
        // O += P @ V  (my 16 dims: kg*16 .. kg*16+15)
        #pragma unroll 4
        for (int ss = 0; ss < 64; ++ss) {
            float p = Ps[qi][ss];
            #pragma unroll
            for (int j = 0; j < 4; ++j) {
                float4 v = *(const float4*)&Vs[ss][kg * 16 + j * 4];
                acc[j*4+0] += p * v.x; acc[j*4+1] += p * v.y;
                acc[j*4+2] += p * v.z; acc[j*4+3] += p * v.w;
            }
        }
    }
    float inv = 1.f / l;
    float* yp = &y[(size_t)(q0 + qi) * DM + cq + kg * 16];
    #pragma unroll
    for (int j = 0; j < 4; ++j) {
        *(float4*)&yp[j * 4] =
            make_float4(acc[j*4]*inv, acc[j*4+1]*inv, acc[j*4+2]*inv, acc[j*4+3]*inv);
    }
}

extern "C" void kernel_launch(void* const* d_in, const int* in_sizes, int n_in,
                              void* d_out, int out_size, void* d_ws, size_t ws_size,
                              hipStream_t stream) {
    const float* x     = (const float*)d_in[0];
    const float* Wqkv  = (const float*)d_in[1];
    const float* bqkv  = (const float*)d_in[2];
    const float* Wproj = (const float*)d_in[3];
    const float* bproj = (const float*)d_in[4];
    float* out = (float*)d_out;

    float* qkv  = (float*)d_ws;                                        // T x 3DM  (48 MB)
    float* yatt = (float*)((char*)d_ws + (size_t)T_SEQ * 3 * DM * 4);  // T x DM   (16 MB)

    dim3 blk(256);
    // qkv = x @ Wqkv^T + b
    gemm_bt_bias<<<dim3(3 * DM / 64, T_SEQ / 64), blk, 0, stream>>>(
        x, Wqkv, bqkv, qkv, T_SEQ, 3 * DM, DM);
    // attention
    attn_causal<<<dim3(T_SEQ / 64, NH), blk, 0, stream>>>(qkv, yatt);
    // out = yatt @ Wproj^T + b
    gemm_bt_bias<<<dim3(DM / 64, T_SEQ / 64), blk, 0, stream>>>(
        yatt, Wproj, bproj, out, T_SEQ, DM, DM);
}

// Round 2
// 769.954 us; speedup vs baseline: 3.7345x; 3.7345x over previous
//
#include <hip/hip_runtime.h>
#include <math.h>
#include <string.h>

#define T_SEQ 4096
#define DM 1024
#define NH 16
#define HD 64

typedef short s8v __attribute__((ext_vector_type(8)));
typedef float f4v __attribute__((ext_vector_type(4)));

__device__ inline unsigned short f2bf(float f) {
    unsigned u; memcpy(&u, &f, 4);
    u = u + 0x7fffu + ((u >> 16) & 1u);   // RNE
    return (unsigned short)(u >> 16);
}

__device__ inline void gld_lds16(const void* g, void* l) {
    __builtin_amdgcn_global_load_lds(
        (const __attribute__((address_space(1))) void*)g,
        (__attribute__((address_space(3))) void*)l, 16, 0, 0);
}

// ---------------- fp32 GEMM, fp32 out:  C = A @ B^T + bias ----------------
__global__ __launch_bounds__(256)
void gemm_bt_bias(const float* __restrict__ A, const float* __restrict__ B,
                  const float* __restrict__ bias, float* __restrict__ C,
                  int M, int N, int K) {
    const int BK = 16;
    __shared__ __align__(16) float As[BK][64 + 4];
    __shared__ __align__(16) float Bs[BK][64 + 4];
    const int tid = threadIdx.x;
    const int tx = tid & 15, ty = tid >> 4;
    const int m0 = blockIdx.y * 64, n0 = blockIdx.x * 64;
    float acc[4][4] = {};
    for (int k0 = 0; k0 < K; k0 += BK) {
        int r = tid >> 2, c = (tid & 3) * 4;
        float4 a = *(const float4*)&A[(size_t)(m0 + r) * K + k0 + c];
        As[c + 0][r] = a.x; As[c + 1][r] = a.y; As[c + 2][r] = a.z; As[c + 3][r] = a.w;
        float4 b = *(const float4*)&B[(size_t)(n0 + r) * K + k0 + c];
        Bs[c + 0][r] = b.x; Bs[c + 1][r] = b.y; Bs[c + 2][r] = b.z; Bs[c + 3][r] = b.w;
        __syncthreads();
        #pragma unroll
        for (int k = 0; k < BK; ++k) {
            float4 a4 = *(const float4*)&As[k][ty * 4];
            float4 b4 = *(const float4*)&Bs[k][tx * 4];
            float av[4] = {a4.x, a4.y, a4.z, a4.w};
            float bv[4] = {b4.x, b4.y, b4.z, b4.w};
            #pragma unroll
            for (int i = 0; i < 4; ++i)
                #pragma unroll
                for (int j = 0; j < 4; ++j) acc[i][j] += av[i] * bv[j];
        }
        __syncthreads();
    }
    #pragma unroll
    for (int i = 0; i < 4; ++i)
        #pragma unroll
        for (int j = 0; j < 4; ++j) {
            int m = m0 + ty * 4 + i, n = n0 + tx * 4 + j;
            C[(size_t)m * N + n] = acc[i][j] + bias[n];
        }
}

// ---------------- fp32 GEMM, bf16 out ----------------
__global__ __launch_bounds__(256)
void gemm_bt_bias_bf16(const float* __restrict__ A, const float* __restrict__ B,
                       const float* __restrict__ bias, unsigned short* __restrict__ C,
                       int M, int N, int K) {
    const int BK = 16;
    __shared__ __align__(16) float As[BK][64 + 4];
    __shared__ __align__(16) float Bs[BK][64 + 4];
    const int tid = threadIdx.x;
    const int tx = tid & 15, ty = tid >> 4;
    const int m0 = blockIdx.y * 64, n0 = blockIdx.x * 64;
    float acc[4][4] = {};
    for (int k0 = 0; k0 < K; k0 += BK) {
        int r = tid >> 2, c = (tid & 3) * 4;
        float4 a = *(const float4*)&A[(size_t)(m0 + r) * K + k0 + c];
        As[c + 0][r] = a.x; As[c + 1][r] = a.y; As[c + 2][r] = a.z; As[c + 3][r] = a.w;
        float4 b = *(const float4*)&B[(size_t)(n0 + r) * K + k0 + c];
        Bs[c + 0][r] = b.x; Bs[c + 1][r] = b.y; Bs[c + 2][r] = b.z; Bs[c + 3][r] = b.w;
        __syncthreads();
        #pragma unroll
        for (int k = 0; k < BK; ++k) {
            float4 a4 = *(const float4*)&As[k][ty * 4];
            float4 b4 = *(const float4*)&Bs[k][tx * 4];
            float av[4] = {a4.x, a4.y, a4.z, a4.w};
            float bv[4] = {b4.x, b4.y, b4.z, b4.w};
            #pragma unroll
            for (int i = 0; i < 4; ++i)
                #pragma unroll
                for (int j = 0; j < 4; ++j) acc[i][j] += av[i] * bv[j];
        }
        __syncthreads();
    }
    #pragma unroll
    for (int i = 0; i < 4; ++i) {
        int m = m0 + ty * 4 + i;
        unsigned short o[4];
        #pragma unroll
        for (int j = 0; j < 4; ++j) {
            int n = n0 + tx * 4 + j;
            o[j] = f2bf(acc[i][j] + bias[n]);
        }
        unsigned long long pk; memcpy(&pk, o, 8);
        *(unsigned long long*)&C[(size_t)m * N + n0 + tx * 4] = pk;
    }
}

// ---------------- MFMA flash attention ----------------
// qkv: (T, 3*DM) bf16 (as ushort). y: (T, DM) fp32.
// Block: 256 thr = 4 waves; wave w owns q-rows [q0+w*16, +16). K-tile = 64 keys.
// Fragment-linear LDS layouts (chunk ch holds the 16B frag lane ch&63 reads):
//   QA[(w*2+half)*64+lane] : Q A-frag   KB[(kb*2+half)*64+lane] : K^T B-frag
//   VB[(ob*2+half)*64+lane] : V  B-frag (staged transposed)
//   PA[w] per-wave: [(half*64+lane)*8] : P A-frag
__global__ __launch_bounds__(256)
void attn_mfma(const unsigned short* __restrict__ qkv, float* __restrict__ y) {
    // swizzle: pair long q-tiles with short ones on the same CU
    const int b = blockIdx.x;
    const int r = b >> 8, i = b & 255;
    const int h = (r << 2) | (i >> 6);
    const int x = i & 63;
    const int qt = (r & 1) ? ((x + r) & 63) : (63 - ((x + r) & 63));

    const int tid = threadIdx.x;
    const int w = tid >> 6, lane = tid & 63;
    const int quad = lane >> 4, l15 = lane & 15;
    const int q0 = qt * 64, cq = h * HD;
    const size_t rs = 3 * DM;

    __shared__ short QA[512 * 8];
    __shared__ short KB[512 * 8];
    __shared__ short VB[512 * 8];
    __shared__ short PA[4][128 * 8];

    // --- stage Q fragment-linear (once) ---
    #pragma unroll
    for (int rr = 0; rr < 2; ++rr) {
        int ch = rr * 256 + tid;
        int w2 = ch >> 7, hf = (ch >> 6) & 1, ln = ch & 63;
        const unsigned short* g = qkv + (size_t)(q0 + w2 * 16 + (ln & 15)) * rs
                                + cq + hf * 32 + ((ln >> 4) << 3);
        gld_lds16(g, &QA[(ch & ~63) * 8]);
    }
    __syncthreads();
    s8v qf0 = *(const s8v*)&QA[((w * 2 + 0) * 64 + lane) * 8];
    s8v qf1 = *(const s8v*)&QA[((w * 2 + 1) * 64 + lane) * 8];

    f4v O[4];
    #pragma unroll
    for (int ob = 0; ob < 4; ++ob) O[ob] = (f4v){0.f, 0.f, 0.f, 0.f};
    float mrun[4] = {-3.0e38f, -3.0e38f, -3.0e38f, -3.0e38f};
    float lrun[4] = {0.f, 0.f, 0.f, 0.f};

    for (int kt = 0; kt <= qt; ++kt) {
        const int k0 = kt * 64;
        __syncthreads();   // previous tile fully consumed
        // K: fragment-linear async copy
        #pragma unroll
        for (int rr = 0; rr < 2; ++rr) {
            int ch = rr * 256 + tid;
            int kb = ch >> 7, hf = (ch >> 6) & 1, ln = ch & 63;
            const unsigned short* g = qkv + (size_t)(k0 + kb * 16 + (ln & 15)) * rs
                                    + DM + cq + hf * 32 + ((ln >> 4) << 3);
            gld_lds16(g, &KB[(ch & ~63) * 8]);
        }
        // V: vector global read, transposed scalar LDS writes into B-frag order
        #pragma unroll
        for (int cc = 0; cc < 2; ++cc) {
            int chunk = tid * 2 + cc;
            int key = chunk >> 3, d0 = (chunk & 7) * 8;
            uint4 vv = *(const uint4*)(qkv + (size_t)(k0 + key) * rs + 2 * DM + cq + d0);
            const unsigned short* vs = (const unsigned short*)&vv;
            int hf = key >> 5, lbase = ((key >> 3) & 3) << 4, j = key & 7;
            #pragma unroll
            for (int ii = 0; ii < 8; ++ii) {
                int d = d0 + ii;
                VB[((((d >> 4) * 2 + hf) * 64) + lbase + (d & 15)) * 8 + j] = vs[ii];
            }
        }
        __syncthreads();

        // --- S = Q K^T (C-layout: row=quad*4+reg (q), col=l15 (key), blocks kb) ---
        f4v S4[4];
        #pragma unroll
        for (int kb = 0; kb < 4; ++kb) {
            s8v k0f = *(const s8v*)&KB[((kb * 2 + 0) * 64 + lane) * 8];
            s8v k1f = *(const s8v*)&KB[((kb * 2 + 1) * 64 + lane) * 8];
            f4v c = (f4v){0.f, 0.f, 0.f, 0.f};
            c = __builtin_amdgcn_mfma_f32_16x16x32_bf16(qf0, k0f, c, 0, 0, 0);
            c = __builtin_amdgcn_mfma_f32_16x16x32_bf16(qf1, k1f, c, 0, 0, 0);
            S4[kb] = c;
        }

        float sv[4][4];
        #pragma unroll
        for (int kb = 0; kb < 4; ++kb)
            #pragma unroll
            for (int rg = 0; rg < 4; ++rg) sv[kb][rg] = S4[kb][rg] * 0.125f;
        if (kt == qt) {  // diagonal tile: mask key > q
            #pragma unroll
            for (int kb = 0; kb < 4; ++kb) {
                int c = kb * 16 + l15;
                #pragma unroll
                for (int rg = 0; rg < 4; ++rg)
                    if (c > w * 16 + quad * 4 + rg) sv[kb][rg] = -3.0e38f;
            }
        }

        // --- online softmax (rows live in 16-lane quad-groups) ---
        float al[4];
        #pragma unroll
        for (int rg = 0; rg < 4; ++rg) {
            float mx = fmaxf(fmaxf(sv[0][rg], sv[1][rg]), fmaxf(sv[2][rg], sv[3][rg]));
            mx = fmaxf(mx, __shfl_xor(mx, 1));
            mx = fmaxf(mx, __shfl_xor(mx, 2));
            mx = fmaxf(mx, __shfl_xor(mx, 4));
            mx = fmaxf(mx, __shfl_xor(mx, 8));
            float mn = fmaxf(mrun[rg], mx);
            al[rg] = __expf(mrun[rg] - mn);
            mrun[rg] = mn;
            float ps = 0.f;
            #pragma unroll
            for (int kb = 0; kb < 4; ++kb) {
                float p = __expf(sv[kb][rg] - mn);
                sv[kb][rg] = p;
                ps += p;
            }
            ps += __shfl_xor(ps, 1);
            ps += __shfl_xor(ps, 2);
            ps += __shfl_xor(ps, 4);
            ps += __shfl_xor(ps, 8);
            lrun[rg] = lrun[rg] * al[rg] + ps;
        }
        #pragma unroll
        for (int ob = 0; ob < 4; ++ob)
            #pragma unroll
            for (int rg = 0; rg < 4; ++rg) O[ob][rg] *= al[rg];

        // --- P: C-layout -> A-frag via per-wave LDS round trip ---
        short* pw = PA[w];
        #pragma unroll
        for (int kb = 0; kb < 4; ++kb) {
            int c = kb * 16 + l15;
            int hf = c >> 5, ln16 = ((c >> 3) & 3) << 4, j = c & 7;
            #pragma unroll
            for (int rg = 0; rg < 4; ++rg)
                pw[(hf * 64 + (quad * 4 + rg + ln16)) * 8 + j] = (short)f2bf(sv[kb][rg]);
        }
        asm volatile("s_waitcnt lgkmcnt(0)" ::: "memory");  // same-wave write->read
        s8v p0 = *(const s8v*)&pw[(0 * 64 + lane) * 8];
        s8v p1 = *(const s8v*)&pw[(1 * 64 + lane) * 8];

        // --- O += P V ---
        #pragma unroll
        for (int ob = 0; ob < 4; ++ob) {
            s8v v0f = *(const s8v*)&VB[((ob * 2 + 0) * 64 + lane) * 8];
            s8v v1f = *(const s8v*)&VB[((ob * 2 + 1) * 64 + lane) * 8];
            O[ob] = __builtin_amdgcn_mfma_f32_16x16x32_bf16(p0, v0f, O[ob], 0, 0, 0);
            O[ob] = __builtin_amdgcn_mfma_f32_16x16x32_bf16(p1, v1f, O[ob], 0, 0, 0);
        }
    }

    // --- epilogue: normalize, write fp32 ---
    #pragma unroll
    for (int rg = 0; rg < 4; ++rg) {
        float inv = 1.f / lrun[rg];
        int qg = q0 + w * 16 + quad * 4 + rg;
        float* yp = &y[(size_t)qg * DM + cq + l15];
        #pragma unroll
        for (int ob = 0; ob < 4; ++ob) yp[ob * 16] = O[ob][rg] * inv;
    }
}

extern "C" void kernel_launch(void* const* d_in, const int* in_sizes, int n_in,
                              void* d_out, int out_size, void* d_ws, size_t ws_size,
                              hipStream_t stream) {
    const float* x     = (const float*)d_in[0];
    const float* Wqkv  = (const float*)d_in[1];
    const float* bqkv  = (const float*)d_in[2];
    const float* Wproj = (const float*)d_in[3];
    const float* bproj = (const float*)d_in[4];
    float* out = (float*)d_out;

    unsigned short* qkvb = (unsigned short*)d_ws;                        // T x 3DM bf16 (24 MB)
    float* yatt = (float*)((char*)d_ws + (size_t)T_SEQ * 3 * DM * 2);    // T x DM  fp32 (16 MB)

    dim3 blk(256);
    gemm_bt_bias_bf16<<<dim3(3 * DM / 64, T_SEQ / 64), blk, 0, stream>>>(
        x, Wqkv, bqkv, qkvb, T_SEQ, 3 * DM, DM);
    attn_mfma<<<dim3(NH * T_SEQ / 64), blk, 0, stream>>>(qkvb, yatt);
    gemm_bt_bias<<<dim3(DM / 64, T_SEQ / 64), blk, 0, stream>>>(
        yatt, Wproj, bproj, out, T_SEQ, DM, DM);
}

// Round 3
// 401.960 us; speedup vs baseline: 7.1534x; 1.9155x over previous
//
#include <hip/hip_runtime.h>
#include <math.h>
#include <string.h>

#define T_SEQ 4096
#define DM 1024
#define NH 16
#define HD 64

typedef short s8v __attribute__((ext_vector_type(8)));
typedef float f4v __attribute__((ext_vector_type(4)));

__device__ inline unsigned short f2bf(float f) {
    unsigned u; memcpy(&u, &f, 4);
    u = u + 0x7fffu + ((u >> 16) & 1u);   // RNE
    return (unsigned short)(u >> 16);
}

__device__ inline void gld_lds16(const void* g, void* l) {
    __builtin_amdgcn_global_load_lds(
        (const __attribute__((address_space(1))) void*)g,
        (__attribute__((address_space(3))) void*)l, 16, 0, 0);
}

// ---------------- fp32 -> bf16 elementwise (8 elems/thread) ----------------
__global__ __launch_bounds__(256)
void cvt_bf16(const float* __restrict__ in, unsigned short* __restrict__ out, int n8) {
    int i = blockIdx.x * 256 + threadIdx.x;
    if (i >= n8) return;
    const float4* p = (const float4*)(in + (size_t)i * 8);
    float4 a = p[0], b = p[1];
    unsigned short o[8] = {f2bf(a.x), f2bf(a.y), f2bf(a.z), f2bf(a.w),
                           f2bf(b.x), f2bf(b.y), f2bf(b.z), f2bf(b.w)};
    uint4 pk; memcpy(&pk, o, 16);
    *(uint4*)(out + (size_t)i * 8) = pk;
}

// ---------------- bf16 MFMA GEMM:  C = A @ B^T + bias ----------------
// A: (M,K) bf16 row-major, B: (N,K) bf16 row-major. 128x128 block tile, BK=32.
// 4 waves; wave w -> 64x64 quadrant (wr=w>>1, wc=w&1), 4x4 grid of 16x16x32 MFMAs.
// LDS fragment-linear: chunk (rg*64+lane) holds A[row=rg*16+(lane&15)][k=(lane>>4)*8 ..+8]
// staged via global_load_lds width=16; ds_read_b128 reads are conflict-free.
template<bool BF16_OUT>
__global__ __launch_bounds__(256)
void gemm_bt_mfma(const unsigned short* __restrict__ A, const unsigned short* __restrict__ B,
                  const float* __restrict__ bias, void* __restrict__ Cout,
                  int M, int N, int K) {
    __shared__ __align__(16) short As[512 * 8];   // 8 KB
    __shared__ __align__(16) short Bs[512 * 8];   // 8 KB
    const int tid = threadIdx.x;
    const int w = tid >> 6, lane = tid & 63;
    const int wr = w >> 1, wc = w & 1;
    const int m0 = blockIdx.y * 128, n0 = blockIdx.x * 128;

    // staging role: wave0->A rows 0-63, wave1->A rows 64-127, wave2/3 -> B same
    const unsigned short* src = (w < 2) ? A : B;
    const int rbase = ((w < 2) ? m0 : n0) + (w & 1) * 64;
    const unsigned short* gsrc = src + (size_t)(rbase + (lane & 15)) * K + ((lane >> 4) * 8);
    short* ldst = ((w < 2) ? As : Bs) + ((w & 1) * 4) * 512;

    f4v acc[4][4];
    #pragma unroll
    for (int i = 0; i < 4; ++i)
        #pragma unroll
        for (int j = 0; j < 4; ++j) acc[i][j] = (f4v){0.f, 0.f, 0.f, 0.f};

    for (int k0 = 0; k0 < K; k0 += 32) {
        __syncthreads();                       // prev tile fully consumed
        #pragma unroll
        for (int i = 0; i < 4; ++i)            // one 16-row group per instr
            gld_lds16(gsrc + (size_t)(i * 16) * K + k0, ldst + i * 512);
        __syncthreads();                       // staging complete (implies vmcnt drain)

        s8v af[4], bf[4];
        #pragma unroll
        for (int i = 0; i < 4; ++i) af[i] = *(const s8v*)&As[((wr * 4 + i) * 64 + lane) * 8];
        #pragma unroll
        for (int j = 0; j < 4; ++j) bf[j] = *(const s8v*)&Bs[((wc * 4 + j) * 64 + lane) * 8];
        #pragma unroll
        for (int i = 0; i < 4; ++i)
            #pragma unroll
            for (int j = 0; j < 4; ++j)
                acc[i][j] = __builtin_amdgcn_mfma_f32_16x16x32_bf16(af[i], bf[j], acc[i][j], 0, 0, 0);
    }

    // epilogue: C row = quad*4+reg, col = lane&15 per 16x16 frag
    const int l15 = lane & 15, quad = lane >> 4;
    float bj[4];
    #pragma unroll
    for (int j = 0; j < 4; ++j) bj[j] = bias[n0 + wc * 64 + j * 16 + l15];
    #pragma unroll
    for (int i = 0; i < 4; ++i) {
        #pragma unroll
        for (int rg = 0; rg < 4; ++rg) {
            int row = m0 + wr * 64 + i * 16 + quad * 4 + rg;
            #pragma unroll
            for (int j = 0; j < 4; ++j) {
                int col = n0 + wc * 64 + j * 16 + l15;
                float v = acc[i][j][rg] + bj[j];
                if (BF16_OUT) ((unsigned short*)Cout)[(size_t)row * N + col] = f2bf(v);
                else          ((float*)Cout)[(size_t)row * N + col] = v;
            }
        }
    }
}

// ---------------- MFMA flash attention ----------------
// qkv: (T, 3*DM) bf16. y: (T, DM) bf16 out.
__global__ __launch_bounds__(256)
void attn_mfma(const unsigned short* __restrict__ qkv, unsigned short* __restrict__ y) {
    // swizzle: pair long q-tiles with short ones on the same CU
    const int b = blockIdx.x;
    const int r = b >> 8, i = b & 255;
    const int h = (r << 2) | (i >> 6);
    const int x = i & 63;
    const int qt = (r & 1) ? ((x + r) & 63) : (63 - ((x + r) & 63));

    const int tid = threadIdx.x;
    const int w = tid >> 6, lane = tid & 63;
    const int quad = lane >> 4, l15 = lane & 15;
    const int q0 = qt * 64, cq = h * HD;
    const size_t rs = 3 * DM;

    __shared__ short QA[512 * 8];
    __shared__ short KB[512 * 8];
    __shared__ short VB[512 * 8];
    __shared__ short PA[4][128 * 8];

    // --- stage Q fragment-linear (once) ---
    #pragma unroll
    for (int rr = 0; rr < 2; ++rr) {
        int ch = rr * 256 + tid;
        int w2 = ch >> 7, hf = (ch >> 6) & 1, ln = ch & 63;
        const unsigned short* g = qkv + (size_t)(q0 + w2 * 16 + (ln & 15)) * rs
                                + cq + hf * 32 + ((ln >> 4) << 3);
        gld_lds16(g, &QA[(ch & ~63) * 8]);
    }
    __syncthreads();
    s8v qf0 = *(const s8v*)&QA[((w * 2 + 0) * 64 + lane) * 8];
    s8v qf1 = *(const s8v*)&QA[((w * 2 + 1) * 64 + lane) * 8];

    f4v O[4];
    #pragma unroll
    for (int ob = 0; ob < 4; ++ob) O[ob] = (f4v){0.f, 0.f, 0.f, 0.f};
    float mrun[4] = {-3.0e38f, -3.0e38f, -3.0e38f, -3.0e38f};
    float lrun[4] = {0.f, 0.f, 0.f, 0.f};

    for (int kt = 0; kt <= qt; ++kt) {
        const int k0 = kt * 64;
        __syncthreads();
        #pragma unroll
        for (int rr = 0; rr < 2; ++rr) {
            int ch = rr * 256 + tid;
            int kb = ch >> 7, hf = (ch >> 6) & 1, ln = ch & 63;
            const unsigned short* g = qkv + (size_t)(k0 + kb * 16 + (ln & 15)) * rs
                                    + DM + cq + hf * 32 + ((ln >> 4) << 3);
            gld_lds16(g, &KB[(ch & ~63) * 8]);
        }
        #pragma unroll
        for (int cc = 0; cc < 2; ++cc) {
            int chunk = tid * 2 + cc;
            int key = chunk >> 3, d0 = (chunk & 7) * 8;
            uint4 vv = *(const uint4*)(qkv + (size_t)(k0 + key) * rs + 2 * DM + cq + d0);
            const unsigned short* vs = (const unsigned short*)&vv;
            int hf = key >> 5, lbase = ((key >> 3) & 3) << 4, j = key & 7;
            #pragma unroll
            for (int ii = 0; ii < 8; ++ii) {
                int d = d0 + ii;
                VB[((((d >> 4) * 2 + hf) * 64) + lbase + (d & 15)) * 8 + j] = vs[ii];
            }
        }
        __syncthreads();

        f4v S4[4];
        #pragma unroll
        for (int kb = 0; kb < 4; ++kb) {
            s8v k0f = *(const s8v*)&KB[((kb * 2 + 0) * 64 + lane) * 8];
            s8v k1f = *(const s8v*)&KB[((kb * 2 + 1) * 64 + lane) * 8];
            f4v c = (f4v){0.f, 0.f, 0.f, 0.f};
            c = __builtin_amdgcn_mfma_f32_16x16x32_bf16(qf0, k0f, c, 0, 0, 0);
            c = __builtin_amdgcn_mfma_f32_16x16x32_bf16(qf1, k1f, c, 0, 0, 0);
            S4[kb] = c;
        }

        float sv[4][4];
        #pragma unroll
        for (int kb = 0; kb < 4; ++kb)
            #pragma unroll
            for (int rg = 0; rg < 4; ++rg) sv[kb][rg] = S4[kb][rg] * 0.125f;
        if (kt == qt) {
            #pragma unroll
            for (int kb = 0; kb < 4; ++kb) {
                int c = kb * 16 + l15;
                #pragma unroll
                for (int rg = 0; rg < 4; ++rg)
                    if (c > w * 16 + quad * 4 + rg) sv[kb][rg] = -3.0e38f;
            }
        }

        float al[4];
        #pragma unroll
        for (int rg = 0; rg < 4; ++rg) {
            float mx = fmaxf(fmaxf(sv[0][rg], sv[1][rg]), fmaxf(sv[2][rg], sv[3][rg]));
            mx = fmaxf(mx, __shfl_xor(mx, 1));
            mx = fmaxf(mx, __shfl_xor(mx, 2));
            mx = fmaxf(mx, __shfl_xor(mx, 4));
            mx = fmaxf(mx, __shfl_xor(mx, 8));
            float mn = fmaxf(mrun[rg], mx);
            al[rg] = __expf(mrun[rg] - mn);
            mrun[rg] = mn;
            float ps = 0.f;
            #pragma unroll
            for (int kb = 0; kb < 4; ++kb) {
                float p = __expf(sv[kb][rg] - mn);
                sv[kb][rg] = p;
                ps += p;
            }
            ps += __shfl_xor(ps, 1);
            ps += __shfl_xor(ps, 2);
            ps += __shfl_xor(ps, 4);
            ps += __shfl_xor(ps, 8);
            lrun[rg] = lrun[rg] * al[rg] + ps;
        }
        #pragma unroll
        for (int ob = 0; ob < 4; ++ob)
            #pragma unroll
            for (int rg = 0; rg < 4; ++rg) O[ob][rg] *= al[rg];

        short* pw = PA[w];
        #pragma unroll
        for (int kb = 0; kb < 4; ++kb) {
            int c = kb * 16 + l15;
            int hf = c >> 5, ln16 = ((c >> 3) & 3) << 4, j = c & 7;
            #pragma unroll
            for (int rg = 0; rg < 4; ++rg)
                pw[(hf * 64 + (quad * 4 + rg + ln16)) * 8 + j] = (short)f2bf(sv[kb][rg]);
        }
        asm volatile("s_waitcnt lgkmcnt(0)" ::: "memory");
        s8v p0 = *(const s8v*)&pw[(0 * 64 + lane) * 8];
        s8v p1 = *(const s8v*)&pw[(1 * 64 + lane) * 8];

        #pragma unroll
        for (int ob = 0; ob < 4; ++ob) {
            s8v v0f = *(const s8v*)&VB[((ob * 2 + 0) * 64 + lane) * 8];
            s8v v1f = *(const s8v*)&VB[((ob * 2 + 1) * 64 + lane) * 8];
            O[ob] = __builtin_amdgcn_mfma_f32_16x16x32_bf16(p0, v0f, O[ob], 0, 0, 0);
            O[ob] = __builtin_amdgcn_mfma_f32_16x16x32_bf16(p1, v1f, O[ob], 0, 0, 0);
        }
    }

    // epilogue: normalize, write bf16 (feeds MFMA GEMM2)
    #pragma unroll
    for (int rg = 0; rg < 4; ++rg) {
        float inv = 1.f / lrun[rg];
        int qg = q0 + w * 16 + quad * 4 + rg;
        unsigned short* yp = &y[(size_t)qg * DM + cq + l15];
        #pragma unroll
        for (int ob = 0; ob < 4; ++ob) yp[ob * 16] = f2bf(O[ob][rg] * inv);
    }
}

extern "C" void kernel_launch(void* const* d_in, const int* in_sizes, int n_in,
                              void* d_out, int out_size, void* d_ws, size_t ws_size,
                              hipStream_t stream) {
    const float* x     = (const float*)d_in[0];
    const float* Wqkv  = (const float*)d_in[1];
    const float* bqkv  = (const float*)d_in[2];
    const float* Wproj = (const float*)d_in[3];
    const float* bproj = (const float*)d_in[4];
    float* out = (float*)d_out;

    char* ws = (char*)d_ws;
    unsigned short* qkvb  = (unsigned short*)(ws);                    // 24 MB
    unsigned short* yattb = (unsigned short*)(ws + (24u << 20));      //  8 MB
    unsigned short* xb    = (unsigned short*)(ws + (32u << 20));      //  8 MB
    unsigned short* wqkvb = (unsigned short*)(ws + (40u << 20));      //  6 MB
    unsigned short* wprjb = (unsigned short*)(ws + (46u << 20));      //  2 MB

    dim3 blk(256);
    // fp32 -> bf16 conversions
    {
        int n8;
        n8 = T_SEQ * DM / 8;
        cvt_bf16<<<dim3((n8 + 255) / 256), blk, 0, stream>>>(x, xb, n8);
        n8 = 3 * DM * DM / 8;
        cvt_bf16<<<dim3((n8 + 255) / 256), blk, 0, stream>>>(Wqkv, wqkvb, n8);
        n8 = DM * DM / 8;
        cvt_bf16<<<dim3((n8 + 255) / 256), blk, 0, stream>>>(Wproj, wprjb, n8);
    }
    // qkv = x @ Wqkv^T + b   (bf16 out)
    gemm_bt_mfma<true><<<dim3(3 * DM / 128, T_SEQ / 128), blk, 0, stream>>>(
        xb, wqkvb, bqkv, qkvb, T_SEQ, 3 * DM, DM);
    // attention (bf16 out)
    attn_mfma<<<dim3(NH * T_SEQ / 64), blk, 0, stream>>>(qkvb, yattb);
    // out = yatt @ Wproj^T + b   (fp32 out)
    gemm_bt_mfma<false><<<dim3(DM / 128, T_SEQ / 128), blk, 0, stream>>>(
        yattb, wprjb, bproj, out, T_SEQ, DM, DM);
}

// Round 4
// 242.164 us; speedup vs baseline: 11.8736x; 1.6599x over previous
//
#include <hip/hip_runtime.h>
#include <math.h>
#include <string.h>

#define T_SEQ 4096
#define DM 1024
#define NH 16
#define HD 64

typedef short s8v __attribute__((ext_vector_type(8)));
typedef float f4v __attribute__((ext_vector_type(4)));

__device__ inline unsigned short f2bf(float f) {
    unsigned u; memcpy(&u, &f, 4);
    u = u + 0x7fffu + ((u >> 16) & 1u);   // RNE
    return (unsigned short)(u >> 16);
}

__device__ inline float exp2fn(float x) {
#if __has_builtin(__builtin_amdgcn_exp2f)
    return __builtin_amdgcn_exp2f(x);
#else
    return exp2f(x);
#endif
}

__device__ inline void gld_lds16(const void* g, void* l) {
    __builtin_amdgcn_global_load_lds(
        (const __attribute__((address_space(1))) void*)g,
        (__attribute__((address_space(3))) void*)l, 16, 0, 0);
}

// ---------------- fp32 -> bf16 elementwise (8 elems/thread) ----------------
__global__ __launch_bounds__(256)
void cvt_bf16(const float* __restrict__ in, unsigned short* __restrict__ out, int n8) {
    int i = blockIdx.x * 256 + threadIdx.x;
    if (i >= n8) return;
    const float4* p = (const float4*)(in + (size_t)i * 8);
    float4 a = p[0], b = p[1];
    unsigned short o[8] = {f2bf(a.x), f2bf(a.y), f2bf(a.z), f2bf(a.w),
                           f2bf(b.x), f2bf(b.y), f2bf(b.z), f2bf(b.w)};
    uint4 pk; memcpy(&pk, o, 16);
    *(uint4*)(out + (size_t)i * 8) = pk;
}

// ---------------- bf16 MFMA GEMM:  C = A @ B^T + bias ----------------
// MODE 0: fp32 row-major out. MODE 1: bf16 row-major out.
// MODE 2: qkv-special — bf16 row-major for n0<2048 (Q,K), transposed bf16 into
//         vT[h][d][t] for n0>=2048 (V region), packed b64 along t.
template<int MODE>
__global__ __launch_bounds__(256)
void gemm_bt_mfma(const unsigned short* __restrict__ A, const unsigned short* __restrict__ B,
                  const float* __restrict__ bias, void* __restrict__ Cout,
                  unsigned short* __restrict__ vT,
                  int M, int N, int K) {
    __shared__ __align__(16) short As[512 * 8];
    __shared__ __align__(16) short Bs[512 * 8];
    const int tid = threadIdx.x;
    const int w = tid >> 6, lane = tid & 63;
    const int wr = w >> 1, wc = w & 1;
    const int m0 = blockIdx.y * 128, n0 = blockIdx.x * 128;

    const unsigned short* src = (w < 2) ? A : B;
    const int rbase = ((w < 2) ? m0 : n0) + (w & 1) * 64;
    const unsigned short* gsrc = src + (size_t)(rbase + (lane & 15)) * K + ((lane >> 4) * 8);
    short* ldst = ((w < 2) ? As : Bs) + ((w & 1) * 4) * 512;

    f4v acc[4][4];
    #pragma unroll
    for (int i = 0; i < 4; ++i)
        #pragma unroll
        for (int j = 0; j < 4; ++j) acc[i][j] = (f4v){0.f, 0.f, 0.f, 0.f};

    for (int k0 = 0; k0 < K; k0 += 32) {
        __syncthreads();
        #pragma unroll
        for (int i = 0; i < 4; ++i)
            gld_lds16(gsrc + (size_t)(i * 16) * K + k0, ldst + i * 512);
        __syncthreads();

        s8v af[4], bf[4];
        #pragma unroll
        for (int i = 0; i < 4; ++i) af[i] = *(const s8v*)&As[((wr * 4 + i) * 64 + lane) * 8];
        #pragma unroll
        for (int j = 0; j < 4; ++j) bf[j] = *(const s8v*)&Bs[((wc * 4 + j) * 64 + lane) * 8];
        #pragma unroll
        for (int i = 0; i < 4; ++i)
            #pragma unroll
            for (int j = 0; j < 4; ++j)
                acc[i][j] = __builtin_amdgcn_mfma_f32_16x16x32_bf16(af[i], bf[j], acc[i][j], 0, 0, 0);
    }

    const int l15 = lane & 15, quad = lane >> 4;
    float bj[4];
    #pragma unroll
    for (int j = 0; j < 4; ++j) bj[j] = bias[n0 + wc * 64 + j * 16 + l15];

    if (MODE == 2 && n0 >= 2 * DM) {
        // V region: write transposed into vT[(h*64+d)*T + t], 4 t's packed.
        #pragma unroll
        for (int i = 0; i < 4; ++i) {
            int tb = m0 + wr * 64 + i * 16 + quad * 4;
            #pragma unroll
            for (int j = 0; j < 4; ++j) {
                int dg = n0 - 2 * DM + wc * 64 + j * 16 + l15;
                unsigned short o[4];
                #pragma unroll
                for (int rg = 0; rg < 4; ++rg) o[rg] = f2bf(acc[i][j][rg] + bj[j]);
                unsigned long long pk; memcpy(&pk, o, 8);
                *(unsigned long long*)&vT[(size_t)dg * T_SEQ + tb] = pk;
            }
        }
    } else {
        #pragma unroll
        for (int i = 0; i < 4; ++i) {
            #pragma unroll
            for (int rg = 0; rg < 4; ++rg) {
                int row = m0 + wr * 64 + i * 16 + quad * 4 + rg;
                #pragma unroll
                for (int j = 0; j < 4; ++j) {
                    int col = n0 + wc * 64 + j * 16 + l15;
                    float v = acc[i][j][rg] + bj[j];
                    if (MODE == 0) ((float*)Cout)[(size_t)row * N + col] = v;
                    else           ((unsigned short*)Cout)[(size_t)row * N + col] = f2bf(v);
                }
            }
        }
    }
}

// ---------------- MFMA flash attention, transposed-score formulation ----------
// S^T = mfma(K, Q): C row = key-local, col = query-local(l15) -> softmax in-lane.
// O^T = mfma(V^T, P^T): alpha/l applied in-lane. V^T pre-transposed globally.
// Block = (head h = b&15, a = b>>4); processes q-tile a then 63-a (65 iters always).
__global__ __launch_bounds__(256, 2)
void attn_mfma2(const unsigned short* __restrict__ qkv,
                const unsigned short* __restrict__ vT,
                unsigned short* __restrict__ y) {
    const int b = blockIdx.x;
    const int h = b & 15, a = b >> 4;
    const int tid = threadIdx.x;
    const int w = tid >> 6, lane = tid & 63;
    const int quad = lane >> 4, l15 = lane & 15;
    const int cq = h * HD, hv = h * HD;
    const size_t rs = 3 * DM;
    const float C2 = 0.1803368851f;   // 0.125 * log2(e)

    __shared__ short KB[2][4096];
    __shared__ short VTs[2][4096];
    __shared__ short QB[4096];
    __shared__ short PB[4][1024];

    for (int ph = 0; ph < 2; ++ph) {
        const int qt = ph ? (63 - a) : a;
        const int q0 = qt * 64;

        __syncthreads();   // previous phase LDS fully consumed
        // stage Q + K/V tile 0
        #pragma unroll
        for (int rr = 0; rr < 2; ++rr) {
            int ch = rr * 256 + tid;
            int blk = ch >> 7, hf = (ch >> 6) & 1, ln = ch & 63;
            const unsigned short* gq = qkv + (size_t)(q0 + blk * 16 + (ln & 15)) * rs
                                     + cq + hf * 32 + ((ln >> 4) << 3);
            gld_lds16(gq, &QB[(ch & ~63) * 8]);
            const unsigned short* gk = qkv + (size_t)(blk * 16 + (ln & 15)) * rs
                                     + DM + cq + hf * 32 + ((ln >> 4) << 3);
            gld_lds16(gk, &KB[0][(ch & ~63) * 8]);
            const unsigned short* gv = vT + (size_t)(hv + blk * 16 + (ln & 15)) * T_SEQ
                                     + hf * 32 + ((ln >> 4) << 3);
            gld_lds16(gv, &VTs[0][(ch & ~63) * 8]);
        }
        __syncthreads();

        s8v qf0 = *(const s8v*)&QB[((w * 2 + 0) * 64 + lane) * 8];
        s8v qf1 = *(const s8v*)&QB[((w * 2 + 1) * 64 + lane) * 8];

        f4v O[4];
        #pragma unroll
        for (int ob = 0; ob < 4; ++ob) O[ob] = (f4v){0.f, 0.f, 0.f, 0.f};
        float mr = -3.0e38f, lr = 0.f;

        for (int kt = 0; kt <= qt; ++kt) {
            const int p = kt & 1;
            if (kt < qt) {   // prefetch next K/V tile into the other buffer
                const int k1 = (kt + 1) * 64;
                #pragma unroll
                for (int rr = 0; rr < 2; ++rr) {
                    int ch = rr * 256 + tid;
                    int blk = ch >> 7, hf = (ch >> 6) & 1, ln = ch & 63;
                    const unsigned short* gk = qkv + (size_t)(k1 + blk * 16 + (ln & 15)) * rs
                                             + DM + cq + hf * 32 + ((ln >> 4) << 3);
                    gld_lds16(gk, &KB[p ^ 1][(ch & ~63) * 8]);
                    const unsigned short* gv = vT + (size_t)(hv + blk * 16 + (ln & 15)) * T_SEQ
                                             + k1 + hf * 32 + ((ln >> 4) << 3);
                    gld_lds16(gv, &VTs[p ^ 1][(ch & ~63) * 8]);
                }
            }

            // --- S^T = K Q^T : st[kb] row=key-local(quad*4+rg), col=query(l15) ---
            f4v st[4];
            #pragma unroll
            for (int kb = 0; kb < 4; ++kb) {
                s8v k0f = *(const s8v*)&KB[p][((kb * 2 + 0) * 64 + lane) * 8];
                s8v k1f = *(const s8v*)&KB[p][((kb * 2 + 1) * 64 + lane) * 8];
                f4v c = (f4v){0.f, 0.f, 0.f, 0.f};
                c = __builtin_amdgcn_mfma_f32_16x16x32_bf16(k0f, qf0, c, 0, 0, 0);
                c = __builtin_amdgcn_mfma_f32_16x16x32_bf16(k1f, qf1, c, 0, 0, 0);
                st[kb] = c;
            }

            float sv[4][4];
            #pragma unroll
            for (int kb = 0; kb < 4; ++kb)
                #pragma unroll
                for (int rg = 0; rg < 4; ++rg) sv[kb][rg] = st[kb][rg];
            if (kt == qt) {   // causal mask on diagonal tile
                #pragma unroll
                for (int kb = 0; kb < 4; ++kb) {
                    #pragma unroll
                    for (int rg = 0; rg < 4; ++rg)
                        if (kb * 16 + quad * 4 + rg > w * 16 + l15) sv[kb][rg] = -3.0e38f;
                }
            }

            // --- online softmax: in-lane over 16 elems + 2 shfls over quads ---
            float mx = sv[0][0];
            #pragma unroll
            for (int kb = 0; kb < 4; ++kb)
                #pragma unroll
                for (int rg = 0; rg < 4; ++rg) mx = fmaxf(mx, sv[kb][rg]);
            mx = fmaxf(mx, __shfl_xor(mx, 16));
            mx = fmaxf(mx, __shfl_xor(mx, 32));
            float mn = fmaxf(mr, mx);
            float alpha = exp2fn((mr - mn) * C2);
            float mc = mn * C2;
            float ps = 0.f;
            #pragma unroll
            for (int kb = 0; kb < 4; ++kb)
                #pragma unroll
                for (int rg = 0; rg < 4; ++rg) {
                    float t = exp2fn(fmaf(sv[kb][rg], C2, -mc));
                    sv[kb][rg] = t;
                    ps += t;
                }
            ps += __shfl_xor(ps, 16);
            ps += __shfl_xor(ps, 32);
            lr = lr * alpha + ps;
            mr = mn;
            #pragma unroll
            for (int ob = 0; ob < 4; ++ob)
                #pragma unroll
                for (int rg = 0; rg < 4; ++rg) O[ob][rg] *= alpha;

            // --- P^T (C-layout) -> B-frag via swizzled per-wave LDS round-trip ---
            short* pw = PB[w];
            #pragma unroll
            for (int kb = 0; kb < 4; ++kb) {
                unsigned u0 = __float_as_uint(sv[kb][0]) + 0x8000u;
                unsigned u1 = __float_as_uint(sv[kb][1]) + 0x8000u;
                unsigned u2 = __float_as_uint(sv[kb][2]) + 0x8000u;
                unsigned u3 = __float_as_uint(sv[kb][3]) + 0x8000u;
                int2 v;
                v.x = (int)__builtin_amdgcn_perm(u1, u0, 0x07060302);
                v.y = (int)__builtin_amdgcn_perm(u3, u2, 0x07060302);
                int c = (kb >> 1) * 64 + ((kb & 1) * 2 + (quad >> 1)) * 16 + l15;
                c ^= ((c >> 3) & 7);
                *(int2*)&pw[c * 8 + (quad & 1) * 4] = v;
            }
            asm volatile("s_waitcnt lgkmcnt(0)" ::: "memory");
            int c0 = lane ^ ((lane >> 3) & 7);
            s8v pf0 = *(const s8v*)&pw[c0 * 8];
            s8v pf1 = *(const s8v*)&pw[(64 + c0) * 8];

            // --- O^T += V^T P^T ---
            #pragma unroll
            for (int ob = 0; ob < 4; ++ob) {
                s8v v0f = *(const s8v*)&VTs[p][((ob * 2 + 0) * 64 + lane) * 8];
                s8v v1f = *(const s8v*)&VTs[p][((ob * 2 + 1) * 64 + lane) * 8];
                O[ob] = __builtin_amdgcn_mfma_f32_16x16x32_bf16(v0f, pf0, O[ob], 0, 0, 0);
                O[ob] = __builtin_amdgcn_mfma_f32_16x16x32_bf16(v1f, pf1, O[ob], 0, 0, 0);
            }
            __syncthreads();   // everyone done with buf p; prefetched buf p^1 landed
        }

        // --- epilogue: O^T col=query(l15), row=dim; normalize in-lane, b64 writes ---
        float linv = 1.f / lr;
        size_t ybase = (size_t)(q0 + w * 16 + l15) * DM + cq;
        #pragma unroll
        for (int ob = 0; ob < 4; ++ob) {
            unsigned short o[4];
            #pragma unroll
            for (int rg = 0; rg < 4; ++rg) o[rg] = f2bf(O[ob][rg] * linv);
            unsigned long long pk; memcpy(&pk, o, 8);
            *(unsigned long long*)&y[ybase + ob * 16 + quad * 4] = pk;
        }
    }
}

extern "C" void kernel_launch(void* const* d_in, const int* in_sizes, int n_in,
                              void* d_out, int out_size, void* d_ws, size_t ws_size,
                              hipStream_t stream) {
    const float* x     = (const float*)d_in[0];
    const float* Wqkv  = (const float*)d_in[1];
    const float* bqkv  = (const float*)d_in[2];
    const float* Wproj = (const float*)d_in[3];
    const float* bproj = (const float*)d_in[4];
    float* out = (float*)d_out;

    char* ws = (char*)d_ws;
    unsigned short* qkvb  = (unsigned short*)(ws);                    // 24 MB (Q,K rows; V unused)
    unsigned short* yattb = (unsigned short*)(ws + (24u << 20));      //  8 MB
    unsigned short* xb    = (unsigned short*)(ws + (32u << 20));      //  8 MB
    unsigned short* wqkvb = (unsigned short*)(ws + (40u << 20));      //  6 MB
    unsigned short* wprjb = (unsigned short*)(ws + (46u << 20));      //  2 MB
    unsigned short* vTb   = (unsigned short*)(ws + (48u << 20));      //  8 MB  [h][d][t]

    dim3 blk(256);
    {
        int n8;
        n8 = T_SEQ * DM / 8;
        cvt_bf16<<<dim3((n8 + 255) / 256), blk, 0, stream>>>(x, xb, n8);
        n8 = 3 * DM * DM / 8;
        cvt_bf16<<<dim3((n8 + 255) / 256), blk, 0, stream>>>(Wqkv, wqkvb, n8);
        n8 = DM * DM / 8;
        cvt_bf16<<<dim3((n8 + 255) / 256), blk, 0, stream>>>(Wproj, wprjb, n8);
    }
    // qkv = x @ Wqkv^T + b : Q,K row-major bf16; V transposed into vTb
    gemm_bt_mfma<2><<<dim3(3 * DM / 128, T_SEQ / 128), blk, 0, stream>>>(
        xb, wqkvb, bqkv, qkvb, vTb, T_SEQ, 3 * DM, DM);
    // attention
    attn_mfma2<<<dim3(NH * 32), blk, 0, stream>>>(qkvb, vTb, yattb);
    // out = yatt @ Wproj^T + b  (fp32 out)
    gemm_bt_mfma<0><<<dim3(DM / 128, T_SEQ / 128), blk, 0, stream>>>(
        yattb, wprjb, bproj, out, nullptr, T_SEQ, DM, DM);
}